// Round 13
// baseline (201.143 us; speedup 1.0000x reference)
//
#include <hip/hip_runtime.h>
#include <hip/hip_bf16.h>

#define N_NODES 50000
#define N_EDGES 1600000
#define N_GRAPHS 512
#define VOCAB 1000
#define EMB 32
#define HID 64
#define N_CLASS 2

#define MAXDEG 96                      // Poisson(32) tail @96 ~ 4e-20/node

// ---- atomic-free CSR build (counting bucket-sort) ----
#define NVEC (N_EDGES / 4)             // 400000 int4 vectors
#define SORT_VPB 1024                  // vectors per block (256 thr x 4)
#define SORT_EPB (SORT_VPB * 4)        // 4096 edges per block
#define SORT_BLOCKS ((NVEC + SORT_VPB - 1) / SORT_VPB)   // 391
#define BSHIFT 7
#define BUCKET_NODES 128
#define NBUCK ((N_NODES + BUCKET_NODES - 1) / BUCKET_NODES)  // 391

#define E1_BLOCKS ((VOCAB * HID + 255) / 256)            // 250

// ---- agg kernels: 8 lanes per node, 8 nodes per wave ----
#define AGG_THREADS (N_NODES * 8)
#define AGG_BLOCKS ((AGG_THREADS + 255) / 256)           // 1563

// ---- lin2_pool: weights in VGPRs, 17 nodes per wave ----
#define L2P_BLOCKS 768                 // 3 blocks/CU co-resident
#define L2P_WAVES (L2P_BLOCKS * 4)     // 3072
#define L2P_CHUNK ((N_NODES + L2P_WAVES - 1) / L2P_WAVES)  // 17

typedef int iv4 __attribute__((ext_vector_type(4)));
typedef unsigned short us;
typedef us usv8 __attribute__((ext_vector_type(8)));
typedef float fv4 __attribute__((ext_vector_type(4)));
typedef unsigned int u32;

__device__ __forceinline__ float bf2f(us u) {
    union { unsigned int i; float f; } c;
    c.i = ((unsigned int)u) << 16;
    return c.f;
}
__device__ __forceinline__ us f2bf(float f) {
    union { __hip_bfloat16 b; us u; } c;
    c.b = __float2bfloat16(f);
    return c.u;
}
__device__ __forceinline__ float rdlane(float v, int k) {
    return __int_as_float(__builtin_amdgcn_readlane(__float_as_int(v), k));
}

// ---------------- K1: fused precompute_e1 + per-block bucket histogram ----------------
__global__ __launch_bounds__(256) void pre_hist_kernel(
        const int* __restrict__ dst, int* __restrict__ hist,
        const float* __restrict__ embed, const float* __restrict__ w1l,
        const float* __restrict__ w1r, us* __restrict__ e1b,
        float* __restrict__ e1r) {
    __shared__ int lh[NBUCK];
    if (blockIdx.x < SORT_BLOCKS) {
        for (int b = threadIdx.x; b < NBUCK; b += 256) lh[b] = 0;
        __syncthreads();
        const iv4* dst4 = (const iv4*)dst;
        int vbase = blockIdx.x * SORT_VPB;
        #pragma unroll
        for (int t = 0; t < 4; ++t) {
            int v = vbase + t * 256 + threadIdx.x;
            if (v < NVEC) {
                iv4 d4 = __builtin_nontemporal_load(&dst4[v]);
                atomicAdd(&lh[d4.x >> BSHIFT], 1);
                atomicAdd(&lh[d4.y >> BSHIFT], 1);
                atomicAdd(&lh[d4.z >> BSHIFT], 1);
                atomicAdd(&lh[d4.w >> BSHIFT], 1);
            }
        }
        __syncthreads();
        for (int b = threadIdx.x; b < NBUCK; b += 256)
            hist[b * SORT_BLOCKS + blockIdx.x] = lh[b];
    } else {
        int id = (blockIdx.x - SORT_BLOCKS) * 256 + threadIdx.x;
        if (id >= VOCAB * HID) return;
        int v = id >> 6, j = id & 63;
        float a = 0.0f, b = 0.0f;
        #pragma unroll
        for (int k = 0; k < EMB; ++k) {
            float ev = embed[v * EMB + k];
            a = fmaf(ev, w1l[k * HID + j], a);
            b = fmaf(ev, w1r[k * HID + j], b);
        }
        e1b[id] = f2bf(a);
        e1r[id] = b;
    }
}

// ---------------- K2: per-bucket exclusive scan over its SORT_BLOCKS counters ----------------
__global__ __launch_bounds__(256) void scan_rows_kernel(int* __restrict__ hist,
                                                        int* __restrict__ btot) {
    int* row = hist + (size_t)blockIdx.x * SORT_BLOCKS;
    __shared__ int wsum[4];
    int tid = threadIdx.x, lane = tid & 63, w = tid >> 6;
    int carry = 0;
    for (int base = 0; base < SORT_BLOCKS; base += 256) {
        int idx = base + tid;
        int v = (idx < SORT_BLOCKS) ? row[idx] : 0;
        int inc = v;
        #pragma unroll
        for (int off = 1; off < 64; off <<= 1) {
            int n = __shfl_up(inc, off, 64);
            if (lane >= off) inc += n;
        }
        if (lane == 63) wsum[w] = inc;
        __syncthreads();
        int woff = 0;
        #pragma unroll
        for (int k = 0; k < 4; ++k) if (k < w) woff += wsum[k];
        if (idx < SORT_BLOCKS) row[idx] = carry + woff + inc - v;
        carry += wsum[0] + wsum[1] + wsum[2] + wsum[3];
        __syncthreads();
    }
    if (tid == 0) btot[blockIdx.x] = carry;
}

// ---------------- K3: scatter with block-local LDS counting sort (u32 entries) ----------------
// LDS entry: (bucket<<23) | (node_in_bucket<<16) | src   (b<512, r<128, src<65536)
// Global ebuf entry: (node_in_bucket<<16) | src  (bucket implied by position).
__global__ __launch_bounds__(256) void scatter_kernel(const int* __restrict__ src,
        const int* __restrict__ dst,
        const int* __restrict__ hist, const int* __restrict__ btot,
        int* __restrict__ boff, u32* __restrict__ ebuf) {
    __shared__ u32 ebuf_l[SORT_EPB];   // 16 KB, bucket-ordered entries
    __shared__ int lh[NBUCK];          // counts -> later write-out base (gbase - lstart)
    __shared__ int lstart[NBUCK];      // block-local exclusive starts
    __shared__ int lcur[NBUCK];        // allocation cursors
    __shared__ int wsum[4];
    int tid = threadIdx.x, lane = tid & 63, w = tid >> 6;
    int blk = blockIdx.x;

    // ---- load this block's edge chunk into registers ----
    const iv4* dst4 = (const iv4*)dst;
    const iv4* src4 = (const iv4*)src;
    int vbase = blk * SORT_VPB;
    iv4 d4s[4], s4s[4];
    bool vok[4];
    #pragma unroll
    for (int t = 0; t < 4; ++t) {
        int v = vbase + t * 256 + tid;
        vok[t] = (v < NVEC);
        if (vok[t]) {
            d4s[t] = __builtin_nontemporal_load(&dst4[v]);
            s4s[t] = __builtin_nontemporal_load(&src4[v]);
        }
    }

    // ---- phase 1: block-local histogram ----
    for (int b = tid; b < NBUCK; b += 256) lh[b] = 0;
    __syncthreads();
    #pragma unroll
    for (int t = 0; t < 4; ++t) {
        if (vok[t]) {
            atomicAdd(&lh[d4s[t].x >> BSHIFT], 1);
            atomicAdd(&lh[d4s[t].y >> BSHIFT], 1);
            atomicAdd(&lh[d4s[t].z >> BSHIFT], 1);
            atomicAdd(&lh[d4s[t].w >> BSHIFT], 1);
        }
    }
    __syncthreads();

    // ---- phase 2: exclusive scan of lh -> lstart (copy to lcur); total in carry ----
    int carry = 0;
    for (int base = 0; base < NBUCK; base += 256) {
        int idx = base + tid;
        int v = (idx < NBUCK) ? lh[idx] : 0;
        int inc = v;
        #pragma unroll
        for (int off = 1; off < 64; off <<= 1) {
            int n = __shfl_up(inc, off, 64);
            if (lane >= off) inc += n;
        }
        if (lane == 63) wsum[w] = inc;
        __syncthreads();
        int woff = 0;
        #pragma unroll
        for (int k = 0; k < 4; ++k) if (k < w) woff += wsum[k];
        if (idx < NBUCK) {
            int ex = carry + woff + inc - v;
            lstart[idx] = ex;
            lcur[idx] = ex;
        }
        carry += wsum[0] + wsum[1] + wsum[2] + wsum[3];
        __syncthreads();
    }
    int total = carry;                 // edges in this block

    // ---- phase 3: place entries bucket-ordered in LDS ----
    #pragma unroll
    for (int t = 0; t < 4; ++t) {
        if (vok[t]) {
            iv4 d4 = d4s[t], s4 = s4s[t];
            #define PLACE(D, S) {                                                \
                int b_ = (D) >> BSHIFT;                                          \
                int p_ = atomicAdd(&lcur[b_], 1);                                \
                ebuf_l[p_] = ((u32)b_ << 23) | ((u32)((D) & (BUCKET_NODES-1)) << 16) \
                           | (u32)(S);                                           \
            }
            PLACE(d4.x, s4.x) PLACE(d4.y, s4.y) PLACE(d4.z, s4.z) PLACE(d4.w, s4.w)
            #undef PLACE
        }
    }
    __syncthreads();

    // ---- phase 4: scan btot -> global bucket bases; lh[b] = boff[b]+hist[b][blk]-lstart[b] ----
    carry = 0;
    for (int base = 0; base < NBUCK; base += 256) {
        int idx = base + tid;
        int v = (idx < NBUCK) ? btot[idx] : 0;
        int inc = v;
        #pragma unroll
        for (int off = 1; off < 64; off <<= 1) {
            int n = __shfl_up(inc, off, 64);
            if (lane >= off) inc += n;
        }
        if (lane == 63) wsum[w] = inc;
        __syncthreads();
        int woff = 0;
        #pragma unroll
        for (int k = 0; k < 4; ++k) if (k < w) woff += wsum[k];
        if (idx < NBUCK) {
            int gb = carry + woff + inc - v;           // boff[idx]
            if (blk == 0) boff[idx] = gb;
            lh[idx] = gb + hist[idx * SORT_BLOCKS + blk] - lstart[idx];
        }
        carry += wsum[0] + wsum[1] + wsum[2] + wsum[3];
        __syncthreads();
    }
    if (blk == 0 && tid == 0) boff[NBUCK] = carry;
    __syncthreads();

    // ---- phase 5: coalesced write-out, strip bucket tag ----
    for (int i = tid; i < total; i += 256) {
        u32 e = ebuf_l[i];
        int b = (int)(e >> 23);
        ebuf[lh[b] + i] = e & 0x7FFFFFu;
    }
}

// ---------------- K4: per-bucket CSR build via LDS slab + dense masked write-out ----------------
// Slab accumulated in LDS (49KB), then streamed out line-aligned: each csr row is
// 384B = 6 full lines, written once, masked to pos<deg -> kills the 4x write amp
// (r7 counters: 26MB written / 8MB fetched for 6.4MB payload with direct scatter).
__global__ __launch_bounds__(256) void csr_bucket_kernel(const u32* __restrict__ ebuf,
        const int* __restrict__ boff, const int* __restrict__ x_ids,
        int* __restrict__ cursor, int* __restrict__ csr, float* __restrict__ gsum) {
    __shared__ int slab[BUCKET_NODES * MAXDEG];        // 49152 B
    __shared__ int cur[BUCKET_NODES];
    int b = blockIdx.x;
    int tid = threadIdx.x;
    for (int r = tid; r < BUCKET_NODES; r += 256) cur[r] = 0;
    // zero gsum (replaces a memset dispatch): blocks 0..127 cover 512*64 floats
    if (b < 128) gsum[b * 256 + tid] = 0.0f;
    __syncthreads();
    int base = boff[b];
    int end  = boff[b + 1];
    int node0 = b << BSHIFT;
    for (int i = base + tid; i < end; i += 256) {
        u32 e = ebuf[i];                               // coalesced 4B read
        int r = (int)(e >> 16);                        // node in bucket (7b)
        int s = (int)(e & 0xFFFFu);                    // src node id
        int pay = (x_ids[s] << 16) | s;                // cls from L2-resident table
        int pos = atomicAdd(&cur[r], 1);               // LDS atomic
        slab[r * MAXDEG + pos] = pay;                  // LDS store
    }
    __syncthreads();
    for (int r = tid; r < BUCKET_NODES; r += 256) {
        int d = node0 + r;
        if (d < N_NODES) cursor[d] = cur[r];
    }
    // dense masked write-out: consecutive j -> consecutive global addresses
    int* crow = csr + (size_t)node0 * MAXDEG;
    for (int j = tid; j < BUCKET_NODES * MAXDEG; j += 256) {
        int r = j / MAXDEG;
        int p = j - r * MAXDEG;
        if (p < cur[r]) crow[j] = slab[j];
    }
}

// ---------------- K5: layer 1 agg + linear + relu, 8 lanes/node (bf16 out only) ----------------
__global__ __launch_bounds__(256) void agg1_lin1_kernel(
        const int* __restrict__ x_ids, const int* __restrict__ csr,
        const int* __restrict__ deg_arr, const us* __restrict__ e1b,
        const float* __restrict__ e1r, const float* __restrict__ b1,
        us* __restrict__ h1b) {
    int tid = blockIdx.x * blockDim.x + threadIdx.x;
    int lane = threadIdx.x & 63;
    int g = lane >> 3, c8 = lane & 7;
    int node = (tid >> 6) * 8 + g;
    bool valid = node < N_NODES;
    int nclamp = valid ? node : 0;
    int deg = valid ? deg_arr[nclamp] : 0;
    const int* crow = csr + (size_t)nclamp * MAXDEG;
    float a0=0.f,a1=0.f,a2=0.f,a3=0.f,a4=0.f,a5=0.f,a6=0.f,a7=0.f;
    for (int k = 0; k < deg; k += 4) {
        iv4 cv = *(const iv4*)(crow + k);      // 16B idx batch, broadcast within group
        #define GATH1(CVAL, T)                                                   \
        if (k + (T) < deg) {                                                     \
            int cls = (CVAL) >> 16;                                              \
            usv8 r = *(const usv8*)(e1b + cls * HID + c8 * 8);                   \
            a0 += bf2f(r[0]); a1 += bf2f(r[1]); a2 += bf2f(r[2]); a3 += bf2f(r[3]); \
            a4 += bf2f(r[4]); a5 += bf2f(r[5]); a6 += bf2f(r[6]); a7 += bf2f(r[7]); \
        }
        GATH1(cv.x, 0) GATH1(cv.y, 1) GATH1(cv.z, 2) GATH1(cv.w, 3)
        #undef GATH1
    }
    if (!valid) return;
    float inv = 1.0f / fmaxf((float)deg, 1.0f);
    int xid = x_ids[nclamp];
    const fv4* er = (const fv4*)(e1r + xid * HID + c8 * 8);
    fv4 e0 = er[0], e1v = er[1];
    const fv4* bb = (const fv4*)(b1 + c8 * 8);
    fv4 b0 = bb[0], b1v = bb[1];
    float h0 = fmaxf(a0 * inv + b0.x + e0.x, 0.0f);
    float h1 = fmaxf(a1 * inv + b0.y + e0.y, 0.0f);
    float h2 = fmaxf(a2 * inv + b0.z + e0.z, 0.0f);
    float h3 = fmaxf(a3 * inv + b0.w + e0.w, 0.0f);
    float h4 = fmaxf(a4 * inv + b1v.x + e1v.x, 0.0f);
    float h5 = fmaxf(a5 * inv + b1v.y + e1v.y, 0.0f);
    float h6 = fmaxf(a6 * inv + b1v.z + e1v.z, 0.0f);
    float h7 = fmaxf(a7 * inv + b1v.w + e1v.w, 0.0f);
    int o = node * HID + c8 * 8;
    usv8 hb;
    hb[0] = f2bf(h0); hb[1] = f2bf(h1); hb[2] = f2bf(h2); hb[3] = f2bf(h3);
    hb[4] = f2bf(h4); hb[5] = f2bf(h5); hb[6] = f2bf(h6); hb[7] = f2bf(h7);
    *(usv8*)(h1b + o) = hb;
}

// ---------------- K6: layer-2 aggregation, 8 lanes/node (bf16 mean out) ----------------
__global__ __launch_bounds__(256) void agg2_mean_kernel(
        const us* __restrict__ h1b, const int* __restrict__ csr,
        const int* __restrict__ deg_arr, us* __restrict__ mean2b) {
    int tid = blockIdx.x * blockDim.x + threadIdx.x;
    int lane = threadIdx.x & 63;
    int g = lane >> 3, c8 = lane & 7;
    int node = (tid >> 6) * 8 + g;
    bool valid = node < N_NODES;
    int nclamp = valid ? node : 0;
    int deg = valid ? deg_arr[nclamp] : 0;
    const int* crow = csr + (size_t)nclamp * MAXDEG;
    float a0=0.f,a1=0.f,a2=0.f,a3=0.f,a4=0.f,a5=0.f,a6=0.f,a7=0.f;
    for (int k = 0; k < deg; k += 4) {
        iv4 cv = *(const iv4*)(crow + k);
        #define GATH2(CVAL, T)                                                   \
        if (k + (T) < deg) {                                                     \
            int nb = (CVAL) & 0xFFFF;                                            \
            usv8 r = *(const usv8*)(h1b + nb * HID + c8 * 8);                    \
            a0 += bf2f(r[0]); a1 += bf2f(r[1]); a2 += bf2f(r[2]); a3 += bf2f(r[3]); \
            a4 += bf2f(r[4]); a5 += bf2f(r[5]); a6 += bf2f(r[6]); a7 += bf2f(r[7]); \
        }
        GATH2(cv.x, 0) GATH2(cv.y, 1) GATH2(cv.z, 2) GATH2(cv.w, 3)
        #undef GATH2
    }
    if (!valid) return;
    float inv = 1.0f / fmaxf((float)deg, 1.0f);
    int o = node * HID + c8 * 8;
    usv8 mb;
    mb[0] = f2bf(a0 * inv); mb[1] = f2bf(a1 * inv);
    mb[2] = f2bf(a2 * inv); mb[3] = f2bf(a3 * inv);
    mb[4] = f2bf(a4 * inv); mb[5] = f2bf(a5 * inv);
    mb[6] = f2bf(a6 * inv); mb[7] = f2bf(a7 * inv);
    *(usv8*)(mean2b + o) = mb;
}

// ---------------- K7: layer 2 linear + relu + pool (bf16 inputs, weights in VGPRs) ----------------
__global__ __launch_bounds__(256) void lin2_pool_kernel(
        const us* __restrict__ mean2b, const us* __restrict__ h1b,
        const float* __restrict__ w2l, const float* __restrict__ b2,
        const float* __restrict__ w2r, const int* __restrict__ batch,
        float* __restrict__ gsum) {
    int lane = threadIdx.x & 63;
    int wv = (blockIdx.x * blockDim.x + threadIdx.x) >> 6;   // global wave id
    int i0 = wv * L2P_CHUNK;
    int i1 = i0 + L2P_CHUNK; if (i1 > N_NODES) i1 = N_NODES;
    if (i0 >= N_NODES) return;
    float wl[HID], wr[HID];
    #pragma unroll
    for (int k = 0; k < HID; ++k) {
        wl[k] = w2l[k * HID + lane];
        wr[k] = w2r[k * HID + lane];
    }
    float bj = b2[lane];
    int curg = __builtin_amdgcn_readfirstlane(batch[i0]);
    float accp = 0.0f;
    float m = bf2f(mean2b[i0 * HID + lane]);
    float h = bf2f(h1b[i0 * HID + lane]);
    for (int i = i0; i < i1; ++i) {
        us mn_u = 0, hn_u = 0;
        if (i + 1 < i1) {                      // prefetch next rows
            mn_u = mean2b[(i + 1) * HID + lane];
            hn_u = h1b[(i + 1) * HID + lane];
        }
        int g = __builtin_amdgcn_readfirstlane(batch[i]);
        if (g != curg) {
            atomicAdd(&gsum[curg * HID + lane], accp);
            accp = 0.0f;
            curg = g;
        }
        float zm = 0.0f, zh = bj;              // split chains: 2x ILP on fma dep
        #pragma unroll
        for (int k = 0; k < HID; ++k) {
            zm = fmaf(rdlane(m, k), wl[k], zm);
            zh = fmaf(rdlane(h, k), wr[k], zh);
        }
        accp += fmaxf(zm + zh, 0.0f);
        m = bf2f(mn_u); h = bf2f(hn_u);
    }
    atomicAdd(&gsum[curg * HID + lane], accp);
}

// ---------------- K8: output: pool-normalize + final linear ----------------
__global__ void out_kernel(const float* __restrict__ gsum, const int* __restrict__ batch,
                           const float* __restrict__ w_out, const float* __restrict__ b_out,
                           float* __restrict__ out) {
    int id = blockIdx.x * blockDim.x + threadIdx.x;
    if (id >= N_GRAPHS * N_CLASS) return;
    int g = id >> 1, c = id & 1;
    int lo = 0, hi = N_NODES;
    while (lo < hi) { int mid = (lo + hi) >> 1; if (batch[mid] < g) lo = mid + 1; else hi = mid; }
    int first = lo;
    lo = 0; hi = N_NODES;
    while (lo < hi) { int mid = (lo + hi) >> 1; if (batch[mid] <= g) lo = mid + 1; else hi = mid; }
    float cnt = (float)(lo - first);
    float inv = 1.0f / fmaxf(cnt, 1.0f);
    float acc = b_out[c];
    #pragma unroll
    for (int j = 0; j < HID; ++j)
        acc = fmaf(gsum[g * HID + j] * inv, w_out[j * N_CLASS + c], acc);
    out[id] = acc;
}

// ---------------- launch: 8 dispatches ----------------

extern "C" void kernel_launch(void* const* d_in, const int* in_sizes, int n_in,
                              void* d_out, int out_size, void* d_ws, size_t ws_size,
                              hipStream_t stream) {
    const int*   x_ids = (const int*)d_in[0];
    const int*   edge  = (const int*)d_in[1];
    const int*   batch = (const int*)d_in[2];
    const float* embed = (const float*)d_in[3];
    const float* w1l   = (const float*)d_in[4];
    const float* b1    = (const float*)d_in[5];
    const float* w1r   = (const float*)d_in[6];
    const float* w2l   = (const float*)d_in[7];
    const float* b2    = (const float*)d_in[8];
    const float* w2r   = (const float*)d_in[9];
    const float* wout  = (const float*)d_in[10];
    const float* bout  = (const float*)d_in[11];
    const int* src = edge;
    const int* dst = edge + N_EDGES;
    float* out = (float*)d_out;

    char* ws = (char*)d_ws;
    size_t off = 0;
    auto alloc = [&](size_t bytes) -> void* {
        void* p = ws + off;
        off += (bytes + 255) & ~(size_t)255;
        return p;
    };
    us*     h1b    = (us*)alloc((size_t)N_NODES * HID * 2);             // 6.4 MB
    u32*    ebuf   = (u32*)alloc((size_t)N_EDGES * 4);                  // 6.4 MB
    int*    csr    = (int*)alloc((size_t)N_NODES * MAXDEG * 4);         // 19.2 MB
    int*    cursor = (int*)alloc((size_t)N_NODES * 4);                  // 200 KB
    int*    hist   = (int*)alloc((size_t)NBUCK * SORT_BLOCKS * 4);      // 611 KB
    int*    btot   = (int*)alloc((size_t)NBUCK * 4);
    int*    boff   = (int*)alloc((size_t)(NBUCK + 1) * 4);
    us*     e1b    = (us*)alloc((size_t)VOCAB * HID * 2);               // 128 KB
    float*  e1r    = (float*)alloc((size_t)VOCAB * HID * 4);            // 256 KB
    float*  gsum   = (float*)alloc((size_t)N_GRAPHS * HID * 4);         // 128 KB

    // mean2b aliases ebuf: ebuf is dead after csr_bucket; agg2_mean then
    // overwrites it (exact size match: 1.6M*4B == 50000*64*2B). Kernel-ordered.
    us* mean2b = (us*)ebuf;

    const int B = 256;
    pre_hist_kernel<<<SORT_BLOCKS + E1_BLOCKS, B, 0, stream>>>(dst, hist,
                                                               embed, w1l, w1r, e1b, e1r);
    scan_rows_kernel<<<NBUCK, B, 0, stream>>>(hist, btot);
    scatter_kernel<<<SORT_BLOCKS, B, 0, stream>>>(src, dst, hist, btot, boff, ebuf);
    csr_bucket_kernel<<<NBUCK, B, 0, stream>>>(ebuf, boff, x_ids, cursor, csr, gsum);
    agg1_lin1_kernel<<<AGG_BLOCKS, B, 0, stream>>>(x_ids, csr, cursor,
                                                   e1b, e1r, b1, h1b);
    agg2_mean_kernel<<<AGG_BLOCKS, B, 0, stream>>>(h1b, csr, cursor, mean2b);
    lin2_pool_kernel<<<L2P_BLOCKS, B, 0, stream>>>(mean2b, h1b, w2l, b2, w2r, batch, gsum);
    out_kernel<<<(N_GRAPHS * N_CLASS + B - 1) / B, B, 0, stream>>>(gsum, batch, wout, bout, out);
}

// Round 14
// 200.707 us; speedup vs baseline: 1.0022x; 1.0022x over previous
//
#include <hip/hip_runtime.h>
#include <hip/hip_bf16.h>

#define N_NODES 50000
#define N_EDGES 1600000
#define N_GRAPHS 512
#define VOCAB 1000
#define EMB 32
#define HID 64
#define N_CLASS 2

#define MAXDEG 96                      // Poisson(32) tail @96 ~ 4e-20/node

// ---- atomic-free CSR build (counting bucket-sort) ----
#define NVEC (N_EDGES / 4)             // 400000 int4 vectors
#define SORT_VPB 1024                  // vectors per block (256 thr x 4)
#define SORT_EPB (SORT_VPB * 4)        // 4096 edges per block
#define SORT_BLOCKS ((NVEC + SORT_VPB - 1) / SORT_VPB)   // 391
#define BSHIFT 7
#define BUCKET_NODES 128
#define NBUCK ((N_NODES + BUCKET_NODES - 1) / BUCKET_NODES)  // 391

#define E1_BLOCKS ((VOCAB * HID + 255) / 256)            // 250

// ---- agg kernels: 8 lanes per node, 8 nodes per wave ----
#define AGG_THREADS (N_NODES * 8)
#define AGG_BLOCKS ((AGG_THREADS + 255) / 256)           // 1563

// ---- lin2_pool: weights in VGPRs, 17 nodes per wave ----
#define L2P_BLOCKS 768                 // 3 blocks/CU co-resident
#define L2P_WAVES (L2P_BLOCKS * 4)     // 3072
#define L2P_CHUNK ((N_NODES + L2P_WAVES - 1) / L2P_WAVES)  // 17

typedef int iv4 __attribute__((ext_vector_type(4)));
typedef unsigned short us;
typedef us usv8 __attribute__((ext_vector_type(8)));
typedef float fv4 __attribute__((ext_vector_type(4)));
typedef unsigned int u32;

__device__ __forceinline__ float bf2f(us u) {
    union { unsigned int i; float f; } c;
    c.i = ((unsigned int)u) << 16;
    return c.f;
}
__device__ __forceinline__ us f2bf(float f) {
    union { __hip_bfloat16 b; us u; } c;
    c.b = __float2bfloat16(f);
    return c.u;
}
__device__ __forceinline__ float rdlane(float v, int k) {
    return __int_as_float(__builtin_amdgcn_readlane(__float_as_int(v), k));
}

// ---------------- K1: fused precompute_e1 + per-block bucket histogram ----------------
__global__ __launch_bounds__(256) void pre_hist_kernel(
        const int* __restrict__ dst, int* __restrict__ hist,
        const float* __restrict__ embed, const float* __restrict__ w1l,
        const float* __restrict__ w1r, us* __restrict__ e1b,
        float* __restrict__ e1r) {
    __shared__ int lh[NBUCK];
    if (blockIdx.x < SORT_BLOCKS) {
        for (int b = threadIdx.x; b < NBUCK; b += 256) lh[b] = 0;
        __syncthreads();
        const iv4* dst4 = (const iv4*)dst;
        int vbase = blockIdx.x * SORT_VPB;
        #pragma unroll
        for (int t = 0; t < 4; ++t) {
            int v = vbase + t * 256 + threadIdx.x;
            if (v < NVEC) {
                iv4 d4 = __builtin_nontemporal_load(&dst4[v]);
                atomicAdd(&lh[d4.x >> BSHIFT], 1);
                atomicAdd(&lh[d4.y >> BSHIFT], 1);
                atomicAdd(&lh[d4.z >> BSHIFT], 1);
                atomicAdd(&lh[d4.w >> BSHIFT], 1);
            }
        }
        __syncthreads();
        for (int b = threadIdx.x; b < NBUCK; b += 256)
            hist[b * SORT_BLOCKS + blockIdx.x] = lh[b];
    } else {
        int id = (blockIdx.x - SORT_BLOCKS) * 256 + threadIdx.x;
        if (id >= VOCAB * HID) return;
        int v = id >> 6, j = id & 63;
        float a = 0.0f, b = 0.0f;
        #pragma unroll
        for (int k = 0; k < EMB; ++k) {
            float ev = embed[v * EMB + k];
            a = fmaf(ev, w1l[k * HID + j], a);
            b = fmaf(ev, w1r[k * HID + j], b);
        }
        e1b[id] = f2bf(a);
        e1r[id] = b;
    }
}

// ---------------- K2: per-bucket exclusive scan over its SORT_BLOCKS counters ----------------
__global__ __launch_bounds__(256) void scan_rows_kernel(int* __restrict__ hist,
                                                        int* __restrict__ btot) {
    int* row = hist + (size_t)blockIdx.x * SORT_BLOCKS;
    __shared__ int wsum[4];
    int tid = threadIdx.x, lane = tid & 63, w = tid >> 6;
    int carry = 0;
    for (int base = 0; base < SORT_BLOCKS; base += 256) {
        int idx = base + tid;
        int v = (idx < SORT_BLOCKS) ? row[idx] : 0;
        int inc = v;
        #pragma unroll
        for (int off = 1; off < 64; off <<= 1) {
            int n = __shfl_up(inc, off, 64);
            if (lane >= off) inc += n;
        }
        if (lane == 63) wsum[w] = inc;
        __syncthreads();
        int woff = 0;
        #pragma unroll
        for (int k = 0; k < 4; ++k) if (k < w) woff += wsum[k];
        if (idx < SORT_BLOCKS) row[idx] = carry + woff + inc - v;
        carry += wsum[0] + wsum[1] + wsum[2] + wsum[3];
        __syncthreads();
    }
    if (tid == 0) btot[blockIdx.x] = carry;
}

// ---------------- K3: scatter with block-local LDS counting sort (u32 entries) ----------------
// LDS entry: (bucket<<23) | (node_in_bucket<<16) | src   (b<512, r<128, src<65536)
// Global ebuf entry: (node_in_bucket<<16) | src  (bucket implied by position).
__global__ __launch_bounds__(256) void scatter_kernel(const int* __restrict__ src,
        const int* __restrict__ dst,
        const int* __restrict__ hist, const int* __restrict__ btot,
        int* __restrict__ boff, u32* __restrict__ ebuf) {
    __shared__ u32 ebuf_l[SORT_EPB];   // 16 KB, bucket-ordered entries
    __shared__ int lh[NBUCK];          // counts -> later write-out base (gbase - lstart)
    __shared__ int lstart[NBUCK];      // block-local exclusive starts
    __shared__ int lcur[NBUCK];        // allocation cursors
    __shared__ int wsum[4];
    int tid = threadIdx.x, lane = tid & 63, w = tid >> 6;
    int blk = blockIdx.x;

    // ---- load this block's edge chunk into registers ----
    const iv4* dst4 = (const iv4*)dst;
    const iv4* src4 = (const iv4*)src;
    int vbase = blk * SORT_VPB;
    iv4 d4s[4], s4s[4];
    bool vok[4];
    #pragma unroll
    for (int t = 0; t < 4; ++t) {
        int v = vbase + t * 256 + tid;
        vok[t] = (v < NVEC);
        if (vok[t]) {
            d4s[t] = __builtin_nontemporal_load(&dst4[v]);
            s4s[t] = __builtin_nontemporal_load(&src4[v]);
        }
    }

    // ---- phase 1: block-local histogram ----
    for (int b = tid; b < NBUCK; b += 256) lh[b] = 0;
    __syncthreads();
    #pragma unroll
    for (int t = 0; t < 4; ++t) {
        if (vok[t]) {
            atomicAdd(&lh[d4s[t].x >> BSHIFT], 1);
            atomicAdd(&lh[d4s[t].y >> BSHIFT], 1);
            atomicAdd(&lh[d4s[t].z >> BSHIFT], 1);
            atomicAdd(&lh[d4s[t].w >> BSHIFT], 1);
        }
    }
    __syncthreads();

    // ---- phase 2: exclusive scan of lh -> lstart (copy to lcur); total in carry ----
    int carry = 0;
    for (int base = 0; base < NBUCK; base += 256) {
        int idx = base + tid;
        int v = (idx < NBUCK) ? lh[idx] : 0;
        int inc = v;
        #pragma unroll
        for (int off = 1; off < 64; off <<= 1) {
            int n = __shfl_up(inc, off, 64);
            if (lane >= off) inc += n;
        }
        if (lane == 63) wsum[w] = inc;
        __syncthreads();
        int woff = 0;
        #pragma unroll
        for (int k = 0; k < 4; ++k) if (k < w) woff += wsum[k];
        if (idx < NBUCK) {
            int ex = carry + woff + inc - v;
            lstart[idx] = ex;
            lcur[idx] = ex;
        }
        carry += wsum[0] + wsum[1] + wsum[2] + wsum[3];
        __syncthreads();
    }
    int total = carry;                 // edges in this block

    // ---- phase 3: place entries bucket-ordered in LDS ----
    #pragma unroll
    for (int t = 0; t < 4; ++t) {
        if (vok[t]) {
            iv4 d4 = d4s[t], s4 = s4s[t];
            #define PLACE(D, S) {                                                \
                int b_ = (D) >> BSHIFT;                                          \
                int p_ = atomicAdd(&lcur[b_], 1);                                \
                ebuf_l[p_] = ((u32)b_ << 23) | ((u32)((D) & (BUCKET_NODES-1)) << 16) \
                           | (u32)(S);                                           \
            }
            PLACE(d4.x, s4.x) PLACE(d4.y, s4.y) PLACE(d4.z, s4.z) PLACE(d4.w, s4.w)
            #undef PLACE
        }
    }
    __syncthreads();

    // ---- phase 4: scan btot -> global bucket bases; lh[b] = boff[b]+hist[b][blk]-lstart[b] ----
    carry = 0;
    for (int base = 0; base < NBUCK; base += 256) {
        int idx = base + tid;
        int v = (idx < NBUCK) ? btot[idx] : 0;
        int inc = v;
        #pragma unroll
        for (int off = 1; off < 64; off <<= 1) {
            int n = __shfl_up(inc, off, 64);
            if (lane >= off) inc += n;
        }
        if (lane == 63) wsum[w] = inc;
        __syncthreads();
        int woff = 0;
        #pragma unroll
        for (int k = 0; k < 4; ++k) if (k < w) woff += wsum[k];
        if (idx < NBUCK) {
            int gb = carry + woff + inc - v;           // boff[idx]
            if (blk == 0) boff[idx] = gb;
            lh[idx] = gb + hist[idx * SORT_BLOCKS + blk] - lstart[idx];
        }
        carry += wsum[0] + wsum[1] + wsum[2] + wsum[3];
        __syncthreads();
    }
    if (blk == 0 && tid == 0) boff[NBUCK] = carry;
    __syncthreads();

    // ---- phase 5: coalesced write-out, strip bucket tag ----
    for (int i = tid; i < total; i += 256) {
        u32 e = ebuf_l[i];
        int b = (int)(e >> 23);
        ebuf[lh[b] + i] = e & 0x7FFFFFu;
    }
}

// ---------------- K4: per-bucket CSR build (direct scatter, 512B LDS, high occupancy) ----------------
// A/B vs r13: reverts the 49KB LDS slab (occupancy 8->3 blocks/CU) to the proven
// direct-scatter form, keeping the u32 ebuf. pay recomputed from L2-hot x_ids.
__global__ __launch_bounds__(256) void csr_bucket_kernel(const u32* __restrict__ ebuf,
        const int* __restrict__ boff, const int* __restrict__ x_ids,
        int* __restrict__ cursor, int* __restrict__ csr, float* __restrict__ gsum) {
    int b = blockIdx.x;
    int tid = threadIdx.x;
    __shared__ int cur[BUCKET_NODES];
    for (int r = tid; r < BUCKET_NODES; r += 256) cur[r] = 0;
    // zero gsum (replaces a memset dispatch): blocks 0..127 cover 512*64 floats
    if (b < 128) gsum[b * 256 + tid] = 0.0f;
    __syncthreads();
    int base = boff[b];
    int end  = boff[b + 1];
    int node0 = b << BSHIFT;
    for (int i = base + tid; i < end; i += 256) {
        u32 e = ebuf[i];                               // coalesced 4B read
        int r = (int)(e >> 16);                        // node in bucket (7b)
        int s = (int)(e & 0xFFFFu);                    // src node id
        int pay = (x_ids[s] << 16) | s;                // cls from L2-resident table
        int pos = atomicAdd(&cur[r], 1);               // LDS atomic
        csr[(size_t)(node0 + r) * MAXDEG + pos] = pay; // store within 49KB L2-local slab
    }
    __syncthreads();
    for (int r = tid; r < BUCKET_NODES; r += 256) {
        int d = node0 + r;
        if (d < N_NODES) cursor[d] = cur[r];
    }
}

// ---------------- K5: layer 1 agg + linear + relu, 8 lanes/node (bf16 out only) ----------------
__global__ __launch_bounds__(256) void agg1_lin1_kernel(
        const int* __restrict__ x_ids, const int* __restrict__ csr,
        const int* __restrict__ deg_arr, const us* __restrict__ e1b,
        const float* __restrict__ e1r, const float* __restrict__ b1,
        us* __restrict__ h1b) {
    int tid = blockIdx.x * blockDim.x + threadIdx.x;
    int lane = threadIdx.x & 63;
    int g = lane >> 3, c8 = lane & 7;
    int node = (tid >> 6) * 8 + g;
    bool valid = node < N_NODES;
    int nclamp = valid ? node : 0;
    int deg = valid ? deg_arr[nclamp] : 0;
    const int* crow = csr + (size_t)nclamp * MAXDEG;
    float a0=0.f,a1=0.f,a2=0.f,a3=0.f,a4=0.f,a5=0.f,a6=0.f,a7=0.f;
    for (int k = 0; k < deg; k += 4) {
        iv4 cv = *(const iv4*)(crow + k);      // 16B idx batch, broadcast within group
        #define GATH1(CVAL, T)                                                   \
        if (k + (T) < deg) {                                                     \
            int cls = (CVAL) >> 16;                                              \
            usv8 r = *(const usv8*)(e1b + cls * HID + c8 * 8);                   \
            a0 += bf2f(r[0]); a1 += bf2f(r[1]); a2 += bf2f(r[2]); a3 += bf2f(r[3]); \
            a4 += bf2f(r[4]); a5 += bf2f(r[5]); a6 += bf2f(r[6]); a7 += bf2f(r[7]); \
        }
        GATH1(cv.x, 0) GATH1(cv.y, 1) GATH1(cv.z, 2) GATH1(cv.w, 3)
        #undef GATH1
    }
    if (!valid) return;
    float inv = 1.0f / fmaxf((float)deg, 1.0f);
    int xid = x_ids[nclamp];
    const fv4* er = (const fv4*)(e1r + xid * HID + c8 * 8);
    fv4 e0 = er[0], e1v = er[1];
    const fv4* bb = (const fv4*)(b1 + c8 * 8);
    fv4 b0 = bb[0], b1v = bb[1];
    float h0 = fmaxf(a0 * inv + b0.x + e0.x, 0.0f);
    float h1 = fmaxf(a1 * inv + b0.y + e0.y, 0.0f);
    float h2 = fmaxf(a2 * inv + b0.z + e0.z, 0.0f);
    float h3 = fmaxf(a3 * inv + b0.w + e0.w, 0.0f);
    float h4 = fmaxf(a4 * inv + b1v.x + e1v.x, 0.0f);
    float h5 = fmaxf(a5 * inv + b1v.y + e1v.y, 0.0f);
    float h6 = fmaxf(a6 * inv + b1v.z + e1v.z, 0.0f);
    float h7 = fmaxf(a7 * inv + b1v.w + e1v.w, 0.0f);
    int o = node * HID + c8 * 8;
    usv8 hb;
    hb[0] = f2bf(h0); hb[1] = f2bf(h1); hb[2] = f2bf(h2); hb[3] = f2bf(h3);
    hb[4] = f2bf(h4); hb[5] = f2bf(h5); hb[6] = f2bf(h6); hb[7] = f2bf(h7);
    *(usv8*)(h1b + o) = hb;
}

// ---------------- K6: layer-2 aggregation, 8 lanes/node (bf16 mean out) ----------------
__global__ __launch_bounds__(256) void agg2_mean_kernel(
        const us* __restrict__ h1b, const int* __restrict__ csr,
        const int* __restrict__ deg_arr, us* __restrict__ mean2b) {
    int tid = blockIdx.x * blockDim.x + threadIdx.x;
    int lane = threadIdx.x & 63;
    int g = lane >> 3, c8 = lane & 7;
    int node = (tid >> 6) * 8 + g;
    bool valid = node < N_NODES;
    int nclamp = valid ? node : 0;
    int deg = valid ? deg_arr[nclamp] : 0;
    const int* crow = csr + (size_t)nclamp * MAXDEG;
    float a0=0.f,a1=0.f,a2=0.f,a3=0.f,a4=0.f,a5=0.f,a6=0.f,a7=0.f;
    for (int k = 0; k < deg; k += 4) {
        iv4 cv = *(const iv4*)(crow + k);
        #define GATH2(CVAL, T)                                                   \
        if (k + (T) < deg) {                                                     \
            int nb = (CVAL) & 0xFFFF;                                            \
            usv8 r = *(const usv8*)(h1b + nb * HID + c8 * 8);                    \
            a0 += bf2f(r[0]); a1 += bf2f(r[1]); a2 += bf2f(r[2]); a3 += bf2f(r[3]); \
            a4 += bf2f(r[4]); a5 += bf2f(r[5]); a6 += bf2f(r[6]); a7 += bf2f(r[7]); \
        }
        GATH2(cv.x, 0) GATH2(cv.y, 1) GATH2(cv.z, 2) GATH2(cv.w, 3)
        #undef GATH2
    }
    if (!valid) return;
    float inv = 1.0f / fmaxf((float)deg, 1.0f);
    int o = node * HID + c8 * 8;
    usv8 mb;
    mb[0] = f2bf(a0 * inv); mb[1] = f2bf(a1 * inv);
    mb[2] = f2bf(a2 * inv); mb[3] = f2bf(a3 * inv);
    mb[4] = f2bf(a4 * inv); mb[5] = f2bf(a5 * inv);
    mb[6] = f2bf(a6 * inv); mb[7] = f2bf(a7 * inv);
    *(usv8*)(mean2b + o) = mb;
}

// ---------------- K7: layer 2 linear + relu + pool (bf16 inputs, weights in VGPRs) ----------------
__global__ __launch_bounds__(256) void lin2_pool_kernel(
        const us* __restrict__ mean2b, const us* __restrict__ h1b,
        const float* __restrict__ w2l, const float* __restrict__ b2,
        const float* __restrict__ w2r, const int* __restrict__ batch,
        float* __restrict__ gsum) {
    int lane = threadIdx.x & 63;
    int wv = (blockIdx.x * blockDim.x + threadIdx.x) >> 6;   // global wave id
    int i0 = wv * L2P_CHUNK;
    int i1 = i0 + L2P_CHUNK; if (i1 > N_NODES) i1 = N_NODES;
    if (i0 >= N_NODES) return;
    float wl[HID], wr[HID];
    #pragma unroll
    for (int k = 0; k < HID; ++k) {
        wl[k] = w2l[k * HID + lane];
        wr[k] = w2r[k * HID + lane];
    }
    float bj = b2[lane];
    int curg = __builtin_amdgcn_readfirstlane(batch[i0]);
    float accp = 0.0f;
    float m = bf2f(mean2b[i0 * HID + lane]);
    float h = bf2f(h1b[i0 * HID + lane]);
    for (int i = i0; i < i1; ++i) {
        us mn_u = 0, hn_u = 0;
        if (i + 1 < i1) {                      // prefetch next rows
            mn_u = mean2b[(i + 1) * HID + lane];
            hn_u = h1b[(i + 1) * HID + lane];
        }
        int g = __builtin_amdgcn_readfirstlane(batch[i]);
        if (g != curg) {
            atomicAdd(&gsum[curg * HID + lane], accp);
            accp = 0.0f;
            curg = g;
        }
        float zm = 0.0f, zh = bj;              // split chains: 2x ILP on fma dep
        #pragma unroll
        for (int k = 0; k < HID; ++k) {
            zm = fmaf(rdlane(m, k), wl[k], zm);
            zh = fmaf(rdlane(h, k), wr[k], zh);
        }
        accp += fmaxf(zm + zh, 0.0f);
        m = bf2f(mn_u); h = bf2f(hn_u);
    }
    atomicAdd(&gsum[curg * HID + lane], accp);
}

// ---------------- K8: output: pool-normalize + final linear ----------------
__global__ void out_kernel(const float* __restrict__ gsum, const int* __restrict__ batch,
                           const float* __restrict__ w_out, const float* __restrict__ b_out,
                           float* __restrict__ out) {
    int id = blockIdx.x * blockDim.x + threadIdx.x;
    if (id >= N_GRAPHS * N_CLASS) return;
    int g = id >> 1, c = id & 1;
    int lo = 0, hi = N_NODES;
    while (lo < hi) { int mid = (lo + hi) >> 1; if (batch[mid] < g) lo = mid + 1; else hi = mid; }
    int first = lo;
    lo = 0; hi = N_NODES;
    while (lo < hi) { int mid = (lo + hi) >> 1; if (batch[mid] <= g) lo = mid + 1; else hi = mid; }
    float cnt = (float)(lo - first);
    float inv = 1.0f / fmaxf(cnt, 1.0f);
    float acc = b_out[c];
    #pragma unroll
    for (int j = 0; j < HID; ++j)
        acc = fmaf(gsum[g * HID + j] * inv, w_out[j * N_CLASS + c], acc);
    out[id] = acc;
}

// ---------------- launch: 8 dispatches ----------------

extern "C" void kernel_launch(void* const* d_in, const int* in_sizes, int n_in,
                              void* d_out, int out_size, void* d_ws, size_t ws_size,
                              hipStream_t stream) {
    const int*   x_ids = (const int*)d_in[0];
    const int*   edge  = (const int*)d_in[1];
    const int*   batch = (const int*)d_in[2];
    const float* embed = (const float*)d_in[3];
    const float* w1l   = (const float*)d_in[4];
    const float* b1    = (const float*)d_in[5];
    const float* w1r   = (const float*)d_in[6];
    const float* w2l   = (const float*)d_in[7];
    const float* b2    = (const float*)d_in[8];
    const float* w2r   = (const float*)d_in[9];
    const float* wout  = (const float*)d_in[10];
    const float* bout  = (const float*)d_in[11];
    const int* src = edge;
    const int* dst = edge + N_EDGES;
    float* out = (float*)d_out;

    char* ws = (char*)d_ws;
    size_t off = 0;
    auto alloc = [&](size_t bytes) -> void* {
        void* p = ws + off;
        off += (bytes + 255) & ~(size_t)255;
        return p;
    };
    us*     h1b    = (us*)alloc((size_t)N_NODES * HID * 2);             // 6.4 MB
    u32*    ebuf   = (u32*)alloc((size_t)N_EDGES * 4);                  // 6.4 MB
    int*    csr    = (int*)alloc((size_t)N_NODES * MAXDEG * 4);         // 19.2 MB
    int*    cursor = (int*)alloc((size_t)N_NODES * 4);                  // 200 KB
    int*    hist   = (int*)alloc((size_t)NBUCK * SORT_BLOCKS * 4);      // 611 KB
    int*    btot   = (int*)alloc((size_t)NBUCK * 4);
    int*    boff   = (int*)alloc((size_t)(NBUCK + 1) * 4);
    us*     e1b    = (us*)alloc((size_t)VOCAB * HID * 2);               // 128 KB
    float*  e1r    = (float*)alloc((size_t)VOCAB * HID * 4);            // 256 KB
    float*  gsum   = (float*)alloc((size_t)N_GRAPHS * HID * 4);         // 128 KB

    // mean2b aliases ebuf: ebuf is dead after csr_bucket; agg2_mean then
    // overwrites it (exact size match: 1.6M*4B == 50000*64*2B). Kernel-ordered.
    us* mean2b = (us*)ebuf;

    const int B = 256;
    pre_hist_kernel<<<SORT_BLOCKS + E1_BLOCKS, B, 0, stream>>>(dst, hist,
                                                               embed, w1l, w1r, e1b, e1r);
    scan_rows_kernel<<<NBUCK, B, 0, stream>>>(hist, btot);
    scatter_kernel<<<SORT_BLOCKS, B, 0, stream>>>(src, dst, hist, btot, boff, ebuf);
    csr_bucket_kernel<<<NBUCK, B, 0, stream>>>(ebuf, boff, x_ids, cursor, csr, gsum);
    agg1_lin1_kernel<<<AGG_BLOCKS, B, 0, stream>>>(x_ids, csr, cursor,
                                                   e1b, e1r, b1, h1b);
    agg2_mean_kernel<<<AGG_BLOCKS, B, 0, stream>>>(h1b, csr, cursor, mean2b);
    lin2_pool_kernel<<<L2P_BLOCKS, B, 0, stream>>>(mean2b, h1b, w2l, b2, w2r, batch, gsum);
    out_kernel<<<(N_GRAPHS * N_CLASS + B - 1) / B, B, 0, stream>>>(gsum, batch, wout, bout, out);
}